// Round 14
// baseline (240.732 us; speedup 1.0000x reference)
//
#include <hip/hip_runtime.h>
#include <math.h>

#define DEV __device__ __forceinline__

typedef __attribute__((ext_vector_type(8))) __bf16 bf16x8;
typedef __attribute__((ext_vector_type(4))) float f32x4;

// ============ prep: weights -> slot-shifted row-padded bf16; BN fold ============
__global__ void prep_weights(
    const float* __restrict__ c1w, const float* __restrict__ c1b,
    const float* __restrict__ g1, const float* __restrict__ b1,
    const float* __restrict__ m1, const float* __restrict__ v1,
    const float* __restrict__ c2w, const float* __restrict__ c2b,
    const float* __restrict__ g2, const float* __restrict__ b2,
    const float* __restrict__ m2, const float* __restrict__ v2,
    const float* __restrict__ c3w, const float* __restrict__ c3b,
    const float* __restrict__ g3, const float* __restrict__ b3,
    const float* __restrict__ m3, const float* __restrict__ v3,
    __bf16* __restrict__ wb1, __bf16* __restrict__ wb2, __bf16* __restrict__ wb3,
    float* __restrict__ sc1, float* __restrict__ sh1,
    float* __restrict__ sc2, float* __restrict__ sh2,
    float* __restrict__ sc3, float* __restrict__ sh3)
{
    int gid = blockIdx.x * 256 + threadIdx.x;
    int gs = gridDim.x * 256;
    for (int e = gid; e < 32 * 192; e += gs) {
        int oc = e / 192, k = e % 192, rr = k >> 3, kw = k & 7;
        wb1[e] = (rr < 21 && kw >= 1) ? (__bf16)c1w[oc * 147 + rr * 7 + kw - 1]
                                      : (__bf16)0.f;
    }
    for (int e = gid; e < 64 * 384; e += gs) {
        int oc = e / 384, k = e % 384, rr = k >> 2, kw = k & 3;
        wb2[e] = (kw >= 1) ? (__bf16)c2w[oc * 288 + rr * 3 + kw - 1] : (__bf16)0.f;
    }
    for (int e = gid; e < 128 * 768; e += gs) {
        int oc = e / 768, k = e % 768, rr = k >> 2, kw = k & 3;
        wb3[e] = (kw >= 1) ? (__bf16)c3w[oc * 576 + rr * 3 + kw - 1] : (__bf16)0.f;
    }
    if (gid < 32) {
        float s = g1[gid] * rsqrtf(v1[gid] + 1e-5f);
        sc1[gid] = s; sh1[gid] = (c1b[gid] - m1[gid]) * s + b1[gid];
    } else if (gid < 96) {
        int i = gid - 32;
        float s = g2[i] * rsqrtf(v2[i] + 1e-5f);
        sc2[i] = s; sh2[i] = (c2b[i] - m2[i]) * s + b2[i];
    } else if (gid < 224) {
        int i = gid - 96;
        float s = g3[i] * rsqrtf(v3[i] + 1e-5f);
        sc3[i] = s; sh3[i] = (c3b[i] - m3[i]) * s + b3[i];
    }
}

// ============ conv1: fp32 direct, BK=64 (3 chunks), 32oc x 128sp ============
__global__ __launch_bounds__(256, 6) void conv1_kernel(
    const float* __restrict__ x,      // (N,3,224,224) fp32
    const __bf16* __restrict__ wb,    // (32,192) slot-shifted
    const float* __restrict__ scale, const float* __restrict__ shift,
    __bf16* __restrict__ out)         // (N,32,56,56)
{
    constexpr int IHW = 224 * 224, OHW = 56 * 56, LDR = 72;
    __shared__ __attribute__((aligned(16))) __bf16 Is[128 * LDR];
    __shared__ __attribute__((aligned(16))) __bf16 Ws[32 * LDR];

    const int tid = threadIdx.x;
    const int sb0 = blockIdx.x * 128;
    const int sm = tid & 127;
    const int kpb = tid >> 7;

    int a_n, a_ih0, a_iw0;
    {
        int m = sb0 + sm;
        a_n = m / OHW;
        int rem = m % OHW;
        a_ih0 = (rem / 56) * 4 - 3;
        a_iw0 = (rem % 56) * 4 - 3;
    }
    unsigned ihok = 0;
    #pragma unroll
    for (int t = 0; t < 7; ++t)
        ihok |= (unsigned)(((a_ih0 + t) >= 0) && ((a_ih0 + t) < 224)) << t;
    const bool left = (a_iw0 < 0);
    const int boff = a_n * 3 * IHW + a_ih0 * 224 + (a_iw0 - 1);  // 16B-aligned

    const int w_oc = tid >> 3, w_j = tid & 7;
    const int wave = tid >> 6, lane = tid & 63;
    const int quad = lane >> 4, l16 = lane & 15;

    f32x4 acc[2][2] = {};

    #pragma unroll
    for (int ci = 0; ci < 3; ++ci) {
        const int k0 = ci * 64;
        bf16x8 hv[4];
        #pragma unroll
        for (int r = 0; r < 4; ++r) {
            const int rr = ci * 8 + kpb * 4 + r;          // compile-time
            if (rr >= 21) {
                hv[r] = (bf16x8){};
            } else {
                const int ic = rr / 7, kh = rr % 7;
                int off = boff + (ic * IHW + kh * 224);
                int o0 = off < 0 ? 0 : off;
                int o1 = (off + 4) < 0 ? 0 : (off + 4);
                float4 A = *(const float4*)(x + o0);
                float4 B = *(const float4*)(x + o1);
                float va[8] = {A.x, A.y, A.z, A.w, B.x, B.y, B.z, B.w};
                bool rok = (ihok >> kh) & 1u;
                #pragma unroll
                for (int j = 0; j < 8; ++j) va[j] = rok ? va[j] : 0.f;
                #pragma unroll
                for (int j = 1; j <= 3; ++j) va[j] = left ? 0.f : va[j];
                bf16x8 h;
                #pragma unroll
                for (int j = 0; j < 8; ++j) h[j] = (__bf16)va[j];
                hv[r] = h;
            }
        }
        bf16x8 wv = *(const bf16x8*)&wb[(size_t)w_oc * 192 + k0 + w_j * 8];

        __syncthreads();
        #pragma unroll
        for (int r = 0; r < 4; ++r)
            *(bf16x8*)&Is[sm * LDR + kpb * 32 + r * 8] = hv[r];
        *(bf16x8*)&Ws[w_oc * LDR + w_j * 8] = wv;
        __syncthreads();

        #pragma unroll
        for (int kk = 0; kk < 2; ++kk) {
            bf16x8 afr[2], bfr[2];
            #pragma unroll
            for (int mt = 0; mt < 2; ++mt)
                afr[mt] = *(const bf16x8*)&Ws[(mt * 16 + l16) * LDR + kk * 32 + quad * 8];
            #pragma unroll
            for (int nt = 0; nt < 2; ++nt)
                bfr[nt] = *(const bf16x8*)&Is[(wave * 32 + nt * 16 + l16) * LDR + kk * 32 + quad * 8];
            #pragma unroll
            for (int mt = 0; mt < 2; ++mt)
                #pragma unroll
                for (int nt = 0; nt < 2; ++nt)
                    acc[mt][nt] = __builtin_amdgcn_mfma_f32_16x16x32_bf16(
                        afr[mt], bfr[nt], acc[mt][nt], 0, 0, 0);
        }
    }

    #pragma unroll
    for (int mt = 0; mt < 2; ++mt) {
        #pragma unroll
        for (int r = 0; r < 4; ++r) {
            int oc = mt * 16 + quad * 4 + r;
            float scl = scale[oc], shf = shift[oc];
            #pragma unroll
            for (int nt = 0; nt < 2; ++nt) {
                int sg = sb0 + wave * 32 + nt * 16 + l16;
                int n = sg / OHW, s = sg % OHW;
                float v = fmaf(acc[mt][nt][r], scl, shf);
                v = v > 0.f ? v : 0.f;
                out[((size_t)n * 32 + oc) * OHW + s] = (__bf16)v;
            }
        }
    }
}

// ============ generic bf16 conv body, BK=64, RW=4 rows ============
// GXS>0: XCD-aware swizzle of blockIdx.x (8 XCDs get contiguous GXS-block
// spatial ranges -> halo re-reads stay in the producing XCD's L2).
template<int NOCT, int IC, int IH, int IW, int OH, int OW, int OC,
         int KTP, int KCH, int GXS>
DEV void conv_body64(
    const __bf16* __restrict__ xo,
    const __bf16* __restrict__ wb,
    const float* __restrict__ scale, const float* __restrict__ shift,
    __bf16* __restrict__ out, __bf16* Is, __bf16* Ws)
{
    constexpr int KS = 3, S = 2, P = 1;
    constexpr int KITER = KCH / 64;
    constexpr int OHW = OH * OW;
    constexpr int IHW = IH * IW;
    constexpr int LDR = 72;
    constexpr int WLD = NOCT / 2;

    const int tid = threadIdx.x;
    int bx = blockIdx.x;
    if (GXS > 0) bx = (bx & 7) * GXS + (bx >> 3);
    const int sb0 = bx * 128;
    const int oc0 = blockIdx.y * (NOCT * 16);

    const int sm = tid & 127;
    const int kpb = tid >> 7;
    int a_n, a_ih0, a_iw0;
    {
        int m = sb0 + sm;
        a_n = m / OHW;
        int rem = m % OHW;
        a_ih0 = (rem / OW) * S - P;
        a_iw0 = (rem % OW) * S - P;
    }
    unsigned ihok = 0;
    #pragma unroll
    for (int t = 0; t < KS; ++t)
        ihok |= (unsigned)(((a_ih0 + t) >= 0) && ((a_ih0 + t) < IH)) << t;
    const bool left = (a_iw0 < 0);
    const __bf16* xp = xo + ((size_t)a_n * IC * IHW + (ptrdiff_t)a_ih0 * IW
                             + (a_iw0 - 1));

    const int wave = tid >> 6, lane = tid & 63;
    const int quad = lane >> 4, l16 = lane & 15;

    f32x4 acc[NOCT][2] = {};

    #pragma unroll
    for (int ci = 0; ci < KITER; ++ci) {
        const int k0 = ci * 64;

        union { unsigned u[16]; bf16x8 v[4]; } Pk;
        #pragma unroll
        for (int r = 0; r < 8; ++r) {
            const int rr = (k0 / 4) + kpb * 8 + r;        // compile-time
            const int ic = rr / KS, kh = rr % KS;
            const unsigned* rp = (const unsigned*)(xp + (ic * IHW + kh * IW));
            unsigned t0 = rp[0], t1 = rp[1];
            bool rok = (ihok >> kh) & 1u;
            t0 = rok ? t0 : 0u;
            t1 = rok ? t1 : 0u;
            t0 = left ? (t0 & 0x0000FFFFu) : t0;          // clear slot 1 (P=1)
            Pk.u[r * 2]     = t0;
            Pk.u[r * 2 + 1] = t1;
        }
        bf16x8 wv[WLD];
        #pragma unroll
        for (int i = 0; i < WLD; ++i) {
            int e = i * 256 + tid;
            wv[i] = *(const bf16x8*)&wb[(size_t)(oc0 + (e >> 3)) * KTP + k0 + (e & 7) * 8];
        }

        __syncthreads();
        #pragma unroll
        for (int q = 0; q < 4; ++q)
            *(bf16x8*)&Is[sm * LDR + kpb * 32 + q * 8] = Pk.v[q];
        #pragma unroll
        for (int i = 0; i < WLD; ++i) {
            int e = i * 256 + tid;
            *(bf16x8*)&Ws[(e >> 3) * LDR + (e & 7) * 8] = wv[i];
        }
        __syncthreads();

        #pragma unroll
        for (int kk = 0; kk < 2; ++kk) {
            bf16x8 afr[NOCT], bfr[2];
            #pragma unroll
            for (int mt = 0; mt < NOCT; ++mt)
                afr[mt] = *(const bf16x8*)&Ws[(mt * 16 + l16) * LDR + kk * 32 + quad * 8];
            #pragma unroll
            for (int nt = 0; nt < 2; ++nt)
                bfr[nt] = *(const bf16x8*)&Is[(wave * 32 + nt * 16 + l16) * LDR + kk * 32 + quad * 8];
            #pragma unroll
            for (int mt = 0; mt < NOCT; ++mt)
                #pragma unroll
                for (int nt = 0; nt < 2; ++nt)
                    acc[mt][nt] = __builtin_amdgcn_mfma_f32_16x16x32_bf16(
                        afr[mt], bfr[nt], acc[mt][nt], 0, 0, 0);
        }
    }

    #pragma unroll
    for (int mt = 0; mt < NOCT; ++mt) {
        #pragma unroll
        for (int r = 0; r < 4; ++r) {
            int oc = oc0 + mt * 16 + quad * 4 + r;
            float scl = scale[oc], shf = shift[oc];
            #pragma unroll
            for (int nt = 0; nt < 2; ++nt) {
                int sg = sb0 + wave * 32 + nt * 16 + l16;
                int n = sg / OHW, s = sg % OHW;
                float v = fmaf(acc[mt][nt][r], scl, shf);
                v = v > 0.f ? v : 0.f;
                out[((size_t)n * OC + oc) * OHW + s] = (__bf16)v;
            }
        }
    }
}

__global__ __launch_bounds__(256, 4) void conv2_kernel(
    const __bf16* __restrict__ xo, const __bf16* __restrict__ wb,
    const float* __restrict__ scale, const float* __restrict__ shift,
    __bf16* __restrict__ out)
{
    __shared__ __attribute__((aligned(16))) __bf16 Is[128 * 72];
    __shared__ __attribute__((aligned(16))) __bf16 Ws[64 * 72];
    conv_body64<4, 32, 56, 56, 28, 28, 64, 384, 384, 98>(   // 784 = 8*98 swizzle
        xo, wb, scale, shift, out, Is, Ws);
}

__global__ __launch_bounds__(256, 6) void conv3_kernel(
    const __bf16* __restrict__ xo, const __bf16* __restrict__ wb,
    const float* __restrict__ scale, const float* __restrict__ shift,
    __bf16* __restrict__ out)
{
    __shared__ __attribute__((aligned(16))) __bf16 Is[128 * 72];
    __shared__ __attribute__((aligned(16))) __bf16 Ws[32 * 72];
    conv_body64<2, 64, 28, 28, 14, 14, 128, 768, 768, 0>(
        xo, wb, scale, shift, out, Is, Ws);
}

// ============ head: coalesced slab -> pool -> linear/tanh -> circuit(regs) -> MLP ============
__global__ __launch_bounds__(256) void head_kernel(
    const __bf16* __restrict__ c3o,      // (N,128,14,14)
    const float* __restrict__ pre_w, const float* __restrict__ pre_b,
    const float* __restrict__ qw,
    const float* __restrict__ pw1, const float* __restrict__ pb1,
    const float* __restrict__ pw2, const float* __restrict__ pb2,
    float* __restrict__ out)             // (N,5)
{
    __shared__ __attribute__((aligned(16))) __bf16 slab[128 * 196]; // 49 KB
    __shared__ float f[512];
    __shared__ float ang[4];
    __shared__ float zexp[4];
    __shared__ float h1[64];

    int b = blockIdx.x;
    int t = threadIdx.x;

    // phase 1: dense coalesced load of the whole (128,14,14) slab into LDS.
    // 128*196 halfs = 3136 bf16x8 chunks; 16B-aligned (slab offset 50176B*n).
    {
        const bf16x8* src = (const bf16x8*)(c3o + (size_t)b * 128 * 196);
        bf16x8* dst = (bf16x8*)slab;
        #pragma unroll
        for (int i = 0; i < 13; ++i) {
            int e = t + i * 256;
            if (e < 3136) dst[e] = src[e];
        }
    }
    __syncthreads();

    // phase 2: pooled features from LDS
    for (int p = t; p < 512; p += 256) {
        int c = p >> 2, i = (p >> 1) & 1, j = p & 1;
        int base = c * 196 + (i * 7) * 14 + j * 7;
        float s = 0.f;
        #pragma unroll
        for (int u = 0; u < 7; ++u)
            #pragma unroll
            for (int v = 0; v < 7; ++v)
                s += (float)slab[base + u * 14 + v];
        f[p] = s * (1.f / 49.f);
    }
    __syncthreads();

    int wv = t >> 6, lane = t & 63;
    float partial = 0.f;
    for (int d = lane; d < 512; d += 64)
        partial += f[d] * pre_w[wv * 512 + d];
    #pragma unroll
    for (int off = 32; off > 0; off >>= 1)
        partial += __shfl_down(partial, off, 64);
    if (lane == 0)
        ang[wv] = tanhf(partial + pre_b[wv]) * 3.14159265358979323846f;
    __syncthreads();

    if (t == 0) {
        float re[16], im[16];
        #pragma unroll
        for (int i = 0; i < 16; ++i) { re[i] = 0.f; im[i] = 0.f; }
        re[0] = 1.f;

        #pragma unroll
        for (int q = 0; q < 4; ++q) {
            const int mask = 8 >> q;
            float c = cosf(ang[q] * 0.5f), s = sinf(ang[q] * 0.5f);
            #pragma unroll
            for (int i = 0; i < 16; ++i) {
                if (i & mask) continue;
                const int j = i | mask;
                float r0 = re[i], i0 = im[i], r1 = re[j], i1 = im[j];
                re[i] = c * r0 - s * r1;  im[i] = c * i0 - s * i1;
                re[j] = s * r0 + c * r1;  im[j] = s * i0 + c * i1;
            }
        }
        #pragma unroll
        for (int l = 0; l < 2; ++l) {
            #pragma unroll
            for (int q = 0; q < 4; ++q) {
                const int mask = 8 >> q;
                const float* qq = qw + (l * 4 + q) * 3;
                {   // RX
                    float c = cosf(qq[0] * 0.5f), s = sinf(qq[0] * 0.5f);
                    #pragma unroll
                    for (int i = 0; i < 16; ++i) {
                        if (i & mask) continue;
                        const int j = i | mask;
                        float r0 = re[i], i0 = im[i], r1 = re[j], i1 = im[j];
                        re[i] = c * r0 + s * i1;  im[i] = c * i0 - s * r1;
                        re[j] = s * i0 + c * r1;  im[j] = -s * r0 + c * i1;
                    }
                }
                {   // RY
                    float c = cosf(qq[1] * 0.5f), s = sinf(qq[1] * 0.5f);
                    #pragma unroll
                    for (int i = 0; i < 16; ++i) {
                        if (i & mask) continue;
                        const int j = i | mask;
                        float r0 = re[i], i0 = im[i], r1 = re[j], i1 = im[j];
                        re[i] = c * r0 - s * r1;  im[i] = c * i0 - s * i1;
                        re[j] = s * r0 + c * r1;  im[j] = s * i0 + c * i1;
                    }
                }
                {   // RZ
                    float c = cosf(qq[2] * 0.5f), s = sinf(qq[2] * 0.5f);
                    #pragma unroll
                    for (int i = 0; i < 16; ++i) {
                        float sg = (i & mask) ? s : -s;
                        float r = re[i], m = im[i];
                        re[i] = c * r - sg * m;
                        im[i] = c * m + sg * r;
                    }
                }
            }
            #pragma unroll
            for (int e = 0; e < 4; ++e) {
                const int cm = 8 >> e, tm = 8 >> ((e + 1) & 3);
                #pragma unroll
                for (int i = 0; i < 16; ++i) {
                    if ((i & cm) && !(i & tm)) {
                        const int j = i | tm;
                        float r = re[i]; re[i] = re[j]; re[j] = r;
                        float m = im[i]; im[i] = im[j]; im[j] = m;
                    }
                }
            }
        }
        #pragma unroll
        for (int q = 0; q < 4; ++q) {
            const int mask = 8 >> q;
            float z = 0.f;
            #pragma unroll
            for (int i = 0; i < 16; ++i) {
                float p2 = re[i] * re[i] + im[i] * im[i];
                z += (i & mask) ? -p2 : p2;
            }
            zexp[q] = z;
        }
    }
    __syncthreads();

    if (t < 64) {
        float s = pb1[t];
        #pragma unroll
        for (int k = 0; k < 4; ++k) s += zexp[k] * pw1[t * 4 + k];
        h1[t] = s > 0.f ? s : 0.f;
    }
    __syncthreads();

    if (t < 5) {
        float s = pb2[t];
        for (int k = 0; k < 64; ++k) s += h1[k] * pw2[t * 64 + k];
        out[b * 5 + t] = s;
    }
}

extern "C" void kernel_launch(void* const* d_in, const int* in_sizes, int n_in,
                              void* d_out, int out_size, void* d_ws, size_t ws_size,
                              hipStream_t stream) {
    const float* x    = (const float*)d_in[0];
    const float* c1w  = (const float*)d_in[1];
    const float* c1b  = (const float*)d_in[2];
    const float* bn1g = (const float*)d_in[3];
    const float* bn1b = (const float*)d_in[4];
    const float* bn1m = (const float*)d_in[5];
    const float* bn1v = (const float*)d_in[6];
    const float* c2w  = (const float*)d_in[7];
    const float* c2b  = (const float*)d_in[8];
    const float* bn2g = (const float*)d_in[9];
    const float* bn2b = (const float*)d_in[10];
    const float* bn2m = (const float*)d_in[11];
    const float* bn2v = (const float*)d_in[12];
    const float* c3w  = (const float*)d_in[13];
    const float* c3bi = (const float*)d_in[14];
    const float* bn3g = (const float*)d_in[15];
    const float* bn3b = (const float*)d_in[16];
    const float* bn3m = (const float*)d_in[17];
    const float* bn3v = (const float*)d_in[18];
    const float* prw  = (const float*)d_in[19];
    const float* prb  = (const float*)d_in[20];
    const float* qw   = (const float*)d_in[21];
    const float* pw1  = (const float*)d_in[22];
    const float* pb1  = (const float*)d_in[23];
    const float* pw2  = (const float*)d_in[24];
    const float* pb2  = (const float*)d_in[25];

    const int N = in_sizes[0] / (3 * 224 * 224);   // 128
    const size_t NC1 = (size_t)N * 32 * 56 * 56;
    const size_t NC2 = (size_t)N * 64 * 28 * 28;
    const size_t NC3 = (size_t)N * 128 * 14 * 14;

    __bf16* ws_h = (__bf16*)d_ws;
    __bf16* c1o = ws_h + 64;
    __bf16* c2o = ws_h + 64 + NC1 + 64 + 64;
    __bf16* c3o = ws_h + 64 + NC1 + 64 + 64 + NC2 + 64;
    __bf16* wb1 = c3o + NC3;
    __bf16* wb2 = wb1 + 32 * 192;
    __bf16* wb3 = wb2 + 64 * 384;
    float* sc1 = (float*)(wb3 + 128 * 768);
    float* sh1 = sc1 + 32;
    float* sc2 = sh1 + 32;  float* sh2 = sc2 + 64;
    float* sc3 = sh2 + 64;  float* sh3 = sc3 + 128;

    prep_weights<<<192, 256, 0, stream>>>(
        c1w, c1b, bn1g, bn1b, bn1m, bn1v,
        c2w, c2b, bn2g, bn2b, bn2m, bn2v,
        c3w, c3bi, bn3g, bn3b, bn3m, bn3v,
        wb1, wb2, wb3, sc1, sh1, sc2, sh2, sc3, sh3);

    conv1_kernel<<<dim3(401408 / 128, 1), 256, 0, stream>>>(x, wb1, sc1, sh1, c1o);
    conv2_kernel<<<dim3(100352 / 128, 1), 256, 0, stream>>>(c1o, wb2, sc2, sh2, c2o);
    conv3_kernel<<<dim3(25088 / 128, 4), 256, 0, stream>>>(c2o, wb3, sc3, sh3, c3o);
    head_kernel<<<N, 256, 0, stream>>>(c3o, prw, prb, qw,
                                       pw1, pb1, pw2, pb2, (float*)d_out);
}

// Round 15
// 234.580 us; speedup vs baseline: 1.0262x; 1.0262x over previous
//
#include <hip/hip_runtime.h>
#include <math.h>

#define DEV __device__ __forceinline__

typedef __attribute__((ext_vector_type(8))) __bf16 bf16x8;
typedef __attribute__((ext_vector_type(4))) float f32x4;

// ============ prep: weights -> slot-shifted row-padded bf16; BN fold ============
__global__ void prep_weights(
    const float* __restrict__ c1w, const float* __restrict__ c1b,
    const float* __restrict__ g1, const float* __restrict__ b1,
    const float* __restrict__ m1, const float* __restrict__ v1,
    const float* __restrict__ c2w, const float* __restrict__ c2b,
    const float* __restrict__ g2, const float* __restrict__ b2,
    const float* __restrict__ m2, const float* __restrict__ v2,
    const float* __restrict__ c3w, const float* __restrict__ c3b,
    const float* __restrict__ g3, const float* __restrict__ b3,
    const float* __restrict__ m3, const float* __restrict__ v3,
    __bf16* __restrict__ wb1, __bf16* __restrict__ wb2, __bf16* __restrict__ wb3,
    float* __restrict__ sc1, float* __restrict__ sh1,
    float* __restrict__ sc2, float* __restrict__ sh2,
    float* __restrict__ sc3, float* __restrict__ sh3)
{
    int gid = blockIdx.x * 256 + threadIdx.x;
    int gs = gridDim.x * 256;
    for (int e = gid; e < 32 * 192; e += gs) {
        int oc = e / 192, k = e % 192, rr = k >> 3, kw = k & 7;
        wb1[e] = (rr < 21 && kw >= 1) ? (__bf16)c1w[oc * 147 + rr * 7 + kw - 1]
                                      : (__bf16)0.f;
    }
    for (int e = gid; e < 64 * 384; e += gs) {
        int oc = e / 384, k = e % 384, rr = k >> 2, kw = k & 3;
        wb2[e] = (kw >= 1) ? (__bf16)c2w[oc * 288 + rr * 3 + kw - 1] : (__bf16)0.f;
    }
    for (int e = gid; e < 128 * 768; e += gs) {
        int oc = e / 768, k = e % 768, rr = k >> 2, kw = k & 3;
        wb3[e] = (kw >= 1) ? (__bf16)c3w[oc * 576 + rr * 3 + kw - 1] : (__bf16)0.f;
    }
    if (gid < 32) {
        float s = g1[gid] * rsqrtf(v1[gid] + 1e-5f);
        sc1[gid] = s; sh1[gid] = (c1b[gid] - m1[gid]) * s + b1[gid];
    } else if (gid < 96) {
        int i = gid - 32;
        float s = g2[i] * rsqrtf(v2[i] + 1e-5f);
        sc2[i] = s; sh2[i] = (c2b[i] - m2[i]) * s + b2[i];
    } else if (gid < 224) {
        int i = gid - 96;
        float s = g3[i] * rsqrtf(v3[i] + 1e-5f);
        sc3[i] = s; sh3[i] = (c3b[i] - m3[i]) * s + b3[i];
    }
}

// ============ conv1: fp32 direct, BK=64 (3 chunks), 32oc x 128sp ============
__global__ __launch_bounds__(256, 6) void conv1_kernel(
    const float* __restrict__ x,      // (N,3,224,224) fp32
    const __bf16* __restrict__ wb,    // (32,192) slot-shifted
    const float* __restrict__ scale, const float* __restrict__ shift,
    __bf16* __restrict__ out)         // (N,32,56,56)
{
    constexpr int IHW = 224 * 224, OHW = 56 * 56, LDR = 72;
    __shared__ __attribute__((aligned(16))) __bf16 Is[128 * LDR];
    __shared__ __attribute__((aligned(16))) __bf16 Ws[32 * LDR];

    const int tid = threadIdx.x;
    const int sb0 = blockIdx.x * 128;
    const int sm = tid & 127;
    const int kpb = tid >> 7;

    int a_n, a_ih0, a_iw0;
    {
        int m = sb0 + sm;
        a_n = m / OHW;
        int rem = m % OHW;
        a_ih0 = (rem / 56) * 4 - 3;
        a_iw0 = (rem % 56) * 4 - 3;
    }
    unsigned ihok = 0;
    #pragma unroll
    for (int t = 0; t < 7; ++t)
        ihok |= (unsigned)(((a_ih0 + t) >= 0) && ((a_ih0 + t) < 224)) << t;
    const bool left = (a_iw0 < 0);
    const int boff = a_n * 3 * IHW + a_ih0 * 224 + (a_iw0 - 1);  // 16B-aligned

    const int w_oc = tid >> 3, w_j = tid & 7;
    const int wave = tid >> 6, lane = tid & 63;
    const int quad = lane >> 4, l16 = lane & 15;

    f32x4 acc[2][2] = {};

    #pragma unroll
    for (int ci = 0; ci < 3; ++ci) {
        const int k0 = ci * 64;
        bf16x8 hv[4];
        #pragma unroll
        for (int r = 0; r < 4; ++r) {
            const int rr = ci * 8 + kpb * 4 + r;          // compile-time
            if (rr >= 21) {
                hv[r] = (bf16x8){};
            } else {
                const int ic = rr / 7, kh = rr % 7;
                int off = boff + (ic * IHW + kh * 224);
                int o0 = off < 0 ? 0 : off;
                int o1 = (off + 4) < 0 ? 0 : (off + 4);
                float4 A = *(const float4*)(x + o0);
                float4 B = *(const float4*)(x + o1);
                float va[8] = {A.x, A.y, A.z, A.w, B.x, B.y, B.z, B.w};
                bool rok = (ihok >> kh) & 1u;
                #pragma unroll
                for (int j = 0; j < 8; ++j) va[j] = rok ? va[j] : 0.f;
                #pragma unroll
                for (int j = 1; j <= 3; ++j) va[j] = left ? 0.f : va[j];
                bf16x8 h;
                #pragma unroll
                for (int j = 0; j < 8; ++j) h[j] = (__bf16)va[j];
                hv[r] = h;
            }
        }
        bf16x8 wv = *(const bf16x8*)&wb[(size_t)w_oc * 192 + k0 + w_j * 8];

        __syncthreads();
        #pragma unroll
        for (int r = 0; r < 4; ++r)
            *(bf16x8*)&Is[sm * LDR + kpb * 32 + r * 8] = hv[r];
        *(bf16x8*)&Ws[w_oc * LDR + w_j * 8] = wv;
        __syncthreads();

        #pragma unroll
        for (int kk = 0; kk < 2; ++kk) {
            bf16x8 afr[2], bfr[2];
            #pragma unroll
            for (int mt = 0; mt < 2; ++mt)
                afr[mt] = *(const bf16x8*)&Ws[(mt * 16 + l16) * LDR + kk * 32 + quad * 8];
            #pragma unroll
            for (int nt = 0; nt < 2; ++nt)
                bfr[nt] = *(const bf16x8*)&Is[(wave * 32 + nt * 16 + l16) * LDR + kk * 32 + quad * 8];
            #pragma unroll
            for (int mt = 0; mt < 2; ++mt)
                #pragma unroll
                for (int nt = 0; nt < 2; ++nt)
                    acc[mt][nt] = __builtin_amdgcn_mfma_f32_16x16x32_bf16(
                        afr[mt], bfr[nt], acc[mt][nt], 0, 0, 0);
        }
    }

    #pragma unroll
    for (int mt = 0; mt < 2; ++mt) {
        #pragma unroll
        for (int r = 0; r < 4; ++r) {
            int oc = mt * 16 + quad * 4 + r;
            float scl = scale[oc], shf = shift[oc];
            #pragma unroll
            for (int nt = 0; nt < 2; ++nt) {
                int sg = sb0 + wave * 32 + nt * 16 + l16;
                int n = sg / OHW, s = sg % OHW;
                float v = fmaf(acc[mt][nt][r], scl, shf);
                v = v > 0.f ? v : 0.f;
                out[((size_t)n * 32 + oc) * OHW + s] = (__bf16)v;
            }
        }
    }
}

// ============ generic bf16 conv body, BK=64, RW=4 rows ============
template<int NOCT, int IC, int IH, int IW, int OH, int OW, int OC,
         int KTP, int KCH, int GXS>
DEV void conv_body64(
    const __bf16* __restrict__ xo,
    const __bf16* __restrict__ wb,
    const float* __restrict__ scale, const float* __restrict__ shift,
    __bf16* __restrict__ out, __bf16* Is, __bf16* Ws)
{
    constexpr int KS = 3, S = 2, P = 1;
    constexpr int KITER = KCH / 64;
    constexpr int OHW = OH * OW;
    constexpr int IHW = IH * IW;
    constexpr int LDR = 72;
    constexpr int WLD = NOCT / 2;

    const int tid = threadIdx.x;
    int bx = blockIdx.x;
    if (GXS > 0) bx = (bx & 7) * GXS + (bx >> 3);
    const int sb0 = bx * 128;
    const int oc0 = blockIdx.y * (NOCT * 16);

    const int sm = tid & 127;
    const int kpb = tid >> 7;
    int a_n, a_ih0, a_iw0;
    {
        int m = sb0 + sm;
        a_n = m / OHW;
        int rem = m % OHW;
        a_ih0 = (rem / OW) * S - P;
        a_iw0 = (rem % OW) * S - P;
    }
    unsigned ihok = 0;
    #pragma unroll
    for (int t = 0; t < KS; ++t)
        ihok |= (unsigned)(((a_ih0 + t) >= 0) && ((a_ih0 + t) < IH)) << t;
    const bool left = (a_iw0 < 0);
    const __bf16* xp = xo + ((size_t)a_n * IC * IHW + (ptrdiff_t)a_ih0 * IW
                             + (a_iw0 - 1));

    const int wave = tid >> 6, lane = tid & 63;
    const int quad = lane >> 4, l16 = lane & 15;

    f32x4 acc[NOCT][2] = {};

    #pragma unroll
    for (int ci = 0; ci < KITER; ++ci) {
        const int k0 = ci * 64;

        union { unsigned u[16]; bf16x8 v[4]; } Pk;
        #pragma unroll
        for (int r = 0; r < 8; ++r) {
            const int rr = (k0 / 4) + kpb * 8 + r;        // compile-time
            const int ic = rr / KS, kh = rr % KS;
            const unsigned* rp = (const unsigned*)(xp + (ic * IHW + kh * IW));
            unsigned t0 = rp[0], t1 = rp[1];
            bool rok = (ihok >> kh) & 1u;
            t0 = rok ? t0 : 0u;
            t1 = rok ? t1 : 0u;
            t0 = left ? (t0 & 0x0000FFFFu) : t0;          // clear slot 1 (P=1)
            Pk.u[r * 2]     = t0;
            Pk.u[r * 2 + 1] = t1;
        }
        bf16x8 wv[WLD];
        #pragma unroll
        for (int i = 0; i < WLD; ++i) {
            int e = i * 256 + tid;
            wv[i] = *(const bf16x8*)&wb[(size_t)(oc0 + (e >> 3)) * KTP + k0 + (e & 7) * 8];
        }

        __syncthreads();
        #pragma unroll
        for (int q = 0; q < 4; ++q)
            *(bf16x8*)&Is[sm * LDR + kpb * 32 + q * 8] = Pk.v[q];
        #pragma unroll
        for (int i = 0; i < WLD; ++i) {
            int e = i * 256 + tid;
            *(bf16x8*)&Ws[(e >> 3) * LDR + (e & 7) * 8] = wv[i];
        }
        __syncthreads();

        #pragma unroll
        for (int kk = 0; kk < 2; ++kk) {
            bf16x8 afr[NOCT], bfr[2];
            #pragma unroll
            for (int mt = 0; mt < NOCT; ++mt)
                afr[mt] = *(const bf16x8*)&Ws[(mt * 16 + l16) * LDR + kk * 32 + quad * 8];
            #pragma unroll
            for (int nt = 0; nt < 2; ++nt)
                bfr[nt] = *(const bf16x8*)&Is[(wave * 32 + nt * 16 + l16) * LDR + kk * 32 + quad * 8];
            #pragma unroll
            for (int mt = 0; mt < NOCT; ++mt)
                #pragma unroll
                for (int nt = 0; nt < 2; ++nt)
                    acc[mt][nt] = __builtin_amdgcn_mfma_f32_16x16x32_bf16(
                        afr[mt], bfr[nt], acc[mt][nt], 0, 0, 0);
        }
    }

    #pragma unroll
    for (int mt = 0; mt < NOCT; ++mt) {
        #pragma unroll
        for (int r = 0; r < 4; ++r) {
            int oc = oc0 + mt * 16 + quad * 4 + r;
            float scl = scale[oc], shf = shift[oc];
            #pragma unroll
            for (int nt = 0; nt < 2; ++nt) {
                int sg = sb0 + wave * 32 + nt * 16 + l16;
                int n = sg / OHW, s = sg % OHW;
                float v = fmaf(acc[mt][nt][r], scl, shf);
                v = v > 0.f ? v : 0.f;
                out[((size_t)n * OC + oc) * OHW + s] = (__bf16)v;
            }
        }
    }
}

__global__ __launch_bounds__(256, 4) void conv2_kernel(
    const __bf16* __restrict__ xo, const __bf16* __restrict__ wb,
    const float* __restrict__ scale, const float* __restrict__ shift,
    __bf16* __restrict__ out)
{
    __shared__ __attribute__((aligned(16))) __bf16 Is[128 * 72];
    __shared__ __attribute__((aligned(16))) __bf16 Ws[64 * 72];
    conv_body64<4, 32, 56, 56, 28, 28, 64, 384, 384, 98>(
        xo, wb, scale, shift, out, Is, Ws);
}

__global__ __launch_bounds__(256, 6) void conv3_kernel(
    const __bf16* __restrict__ xo, const __bf16* __restrict__ wb,
    const float* __restrict__ scale, const float* __restrict__ shift,
    __bf16* __restrict__ out)
{
    __shared__ __attribute__((aligned(16))) __bf16 Is[128 * 72];
    __shared__ __attribute__((aligned(16))) __bf16 Ws[32 * 72];
    conv_body64<2, 64, 28, 28, 14, 14, 128, 768, 768, 0>(
        xo, wb, scale, shift, out, Is, Ws);
}

// ============ head: slab -> pool -> linear/tanh -> SHUFFLE circuit -> MLP ============
// Statevector: 16 lanes x (re,im) scalars -- cannot spill. Gates = shfl_xor +
// FMA; RX needs no predicate (re'=c*re+s*shfl(im), im'=c*im-s*shfl(re)).
__global__ __launch_bounds__(256) void head_kernel(
    const __bf16* __restrict__ c3o,      // (N,128,14,14)
    const float* __restrict__ pre_w, const float* __restrict__ pre_b,
    const float* __restrict__ qw,
    const float* __restrict__ pw1, const float* __restrict__ pb1,
    const float* __restrict__ pw2, const float* __restrict__ pb2,
    float* __restrict__ out)             // (N,5)
{
    __shared__ __attribute__((aligned(16))) __bf16 slab[128 * 196]; // 49 KB
    __shared__ float f[512];
    __shared__ float ang[4];
    __shared__ float zexp[4];
    __shared__ float h1[64];

    int b = blockIdx.x;
    int t = threadIdx.x;

    // phase 1: dense coalesced load of the whole (128,14,14) slab into LDS
    {
        const bf16x8* src = (const bf16x8*)(c3o + (size_t)b * 128 * 196);
        bf16x8* dst = (bf16x8*)slab;
        #pragma unroll
        for (int i = 0; i < 13; ++i) {
            int e = t + i * 256;
            if (e < 3136) dst[e] = src[e];
        }
    }
    __syncthreads();

    // phase 2: pooled features from LDS
    for (int p = t; p < 512; p += 256) {
        int c = p >> 2, i = (p >> 1) & 1, j = p & 1;
        int base = c * 196 + (i * 7) * 14 + j * 7;
        float s = 0.f;
        #pragma unroll
        for (int u = 0; u < 7; ++u)
            #pragma unroll
            for (int v = 0; v < 7; ++v)
                s += (float)slab[base + u * 14 + v];
        f[p] = s * (1.f / 49.f);
    }
    __syncthreads();

    int wv = t >> 6, lane = t & 63;
    float partial = 0.f;
    for (int d = lane; d < 512; d += 64)
        partial += f[d] * pre_w[wv * 512 + d];
    #pragma unroll
    for (int off = 32; off > 0; off >>= 1)
        partial += __shfl_down(partial, off, 64);
    if (lane == 0)
        ang[wv] = tanhf(partial + pre_b[wv]) * 3.14159265358979323846f;
    __syncthreads();

    // phase 3: 4-qubit circuit on lanes 0..15 (amplitude idx = lane)
    if (t < 16) {
        const int i = t;
        float re = (i == 0) ? 1.f : 0.f;
        float im = 0.f;

        // initial RY(angles[q])
        #pragma unroll
        for (int q = 0; q < 4; ++q) {
            const int m = 8 >> q;
            float th = ang[q] * 0.5f;
            float c = cosf(th), s = sinf(th);
            float pr = __shfl_xor(re, m, 64);
            float pi = __shfl_xor(im, m, 64);
            float ts = (i & m) ? s : -s;
            re = c * re + ts * pr;
            im = c * im + ts * pi;
        }
        #pragma unroll
        for (int l = 0; l < 2; ++l) {
            #pragma unroll
            for (int q = 0; q < 4; ++q) {
                const int m = 8 >> q;
                const float* qq = qw + (l * 4 + q) * 3;
                {   // RX: uniform across pair
                    float th = qq[0] * 0.5f;
                    float c = cosf(th), s = sinf(th);
                    float pr = __shfl_xor(re, m, 64);
                    float pi = __shfl_xor(im, m, 64);
                    float rn = c * re + s * pi;
                    im = c * im - s * pr;
                    re = rn;
                }
                {   // RY
                    float th = qq[1] * 0.5f;
                    float c = cosf(th), s = sinf(th);
                    float pr = __shfl_xor(re, m, 64);
                    float pi = __shfl_xor(im, m, 64);
                    float ts = (i & m) ? s : -s;
                    re = c * re + ts * pr;
                    im = c * im + ts * pi;
                }
                {   // RZ: diagonal
                    float th = qq[2] * 0.5f;
                    float c = cosf(th), s = sinf(th);
                    float ts = (i & m) ? s : -s;
                    float rn = c * re - ts * im;
                    im = c * im + ts * re;
                    re = rn;
                }
            }
            // ring CNOTs
            #pragma unroll
            for (int e = 0; e < 4; ++e) {
                const int cm = 8 >> e, tm = 8 >> ((e + 1) & 3);
                float pr = __shfl_xor(re, tm, 64);
                float pi = __shfl_xor(im, tm, 64);
                bool sw = (i & cm) != 0;
                re = sw ? pr : re;
                im = sw ? pi : im;
            }
        }
        // Z expvals: 4 signed butterfly reductions over 16 lanes
        float p2 = re * re + im * im;
        #pragma unroll
        for (int q = 0; q < 4; ++q) {
            const int m = 8 >> q;
            float v = (i & m) ? -p2 : p2;
            v += __shfl_xor(v, 1, 64);
            v += __shfl_xor(v, 2, 64);
            v += __shfl_xor(v, 4, 64);
            v += __shfl_xor(v, 8, 64);
            if (i == 0) zexp[q] = v;
        }
    }
    __syncthreads();

    if (t < 64) {
        float s = pb1[t];
        #pragma unroll
        for (int k = 0; k < 4; ++k) s += zexp[k] * pw1[t * 4 + k];
        h1[t] = s > 0.f ? s : 0.f;
    }
    __syncthreads();

    if (t < 5) {
        float s = pb2[t];
        for (int k = 0; k < 64; ++k) s += h1[k] * pw2[t * 64 + k];
        out[b * 5 + t] = s;
    }
}

extern "C" void kernel_launch(void* const* d_in, const int* in_sizes, int n_in,
                              void* d_out, int out_size, void* d_ws, size_t ws_size,
                              hipStream_t stream) {
    const float* x    = (const float*)d_in[0];
    const float* c1w  = (const float*)d_in[1];
    const float* c1b  = (const float*)d_in[2];
    const float* bn1g = (const float*)d_in[3];
    const float* bn1b = (const float*)d_in[4];
    const float* bn1m = (const float*)d_in[5];
    const float* bn1v = (const float*)d_in[6];
    const float* c2w  = (const float*)d_in[7];
    const float* c2b  = (const float*)d_in[8];
    const float* bn2g = (const float*)d_in[9];
    const float* bn2b = (const float*)d_in[10];
    const float* bn2m = (const float*)d_in[11];
    const float* bn2v = (const float*)d_in[12];
    const float* c3w  = (const float*)d_in[13];
    const float* c3bi = (const float*)d_in[14];
    const float* bn3g = (const float*)d_in[15];
    const float* bn3b = (const float*)d_in[16];
    const float* bn3m = (const float*)d_in[17];
    const float* bn3v = (const float*)d_in[18];
    const float* prw  = (const float*)d_in[19];
    const float* prb  = (const float*)d_in[20];
    const float* qw   = (const float*)d_in[21];
    const float* pw1  = (const float*)d_in[22];
    const float* pb1  = (const float*)d_in[23];
    const float* pw2  = (const float*)d_in[24];
    const float* pb2  = (const float*)d_in[25];

    const int N = in_sizes[0] / (3 * 224 * 224);   // 128
    const size_t NC1 = (size_t)N * 32 * 56 * 56;
    const size_t NC2 = (size_t)N * 64 * 28 * 28;
    const size_t NC3 = (size_t)N * 128 * 14 * 14;

    __bf16* ws_h = (__bf16*)d_ws;
    __bf16* c1o = ws_h + 64;
    __bf16* c2o = ws_h + 64 + NC1 + 64 + 64;
    __bf16* c3o = ws_h + 64 + NC1 + 64 + 64 + NC2 + 64;
    __bf16* wb1 = c3o + NC3;
    __bf16* wb2 = wb1 + 32 * 192;
    __bf16* wb3 = wb2 + 64 * 384;
    float* sc1 = (float*)(wb3 + 128 * 768);
    float* sh1 = sc1 + 32;
    float* sc2 = sh1 + 32;  float* sh2 = sc2 + 64;
    float* sc3 = sh2 + 64;  float* sh3 = sc3 + 128;

    prep_weights<<<192, 256, 0, stream>>>(
        c1w, c1b, bn1g, bn1b, bn1m, bn1v,
        c2w, c2b, bn2g, bn2b, bn2m, bn2v,
        c3w, c3bi, bn3g, bn3b, bn3m, bn3v,
        wb1, wb2, wb3, sc1, sh1, sc2, sh2, sc3, sh3);

    conv1_kernel<<<dim3(401408 / 128, 1), 256, 0, stream>>>(x, wb1, sc1, sh1, c1o);
    conv2_kernel<<<dim3(100352 / 128, 1), 256, 0, stream>>>(c1o, wb2, sc2, sh2, c2o);
    conv3_kernel<<<dim3(25088 / 128, 4), 256, 0, stream>>>(c2o, wb3, sc3, sh3, c3o);
    head_kernel<<<N, 256, 0, stream>>>(c3o, prw, prb, qw,
                                       pw1, pb1, pw2, pb2, (float*)d_out);
}

// Round 16
// 233.456 us; speedup vs baseline: 1.0312x; 1.0048x over previous
//
#include <hip/hip_runtime.h>
#include <math.h>

#define DEV __device__ __forceinline__

typedef __attribute__((ext_vector_type(8))) __bf16 bf16x8;
typedef __attribute__((ext_vector_type(4))) float f32x4;

// ============ prep: weights -> slot-shifted row-padded bf16; BN fold ============
__global__ void prep_weights(
    const float* __restrict__ c1w, const float* __restrict__ c1b,
    const float* __restrict__ g1, const float* __restrict__ b1,
    const float* __restrict__ m1, const float* __restrict__ v1,
    const float* __restrict__ c2w, const float* __restrict__ c2b,
    const float* __restrict__ g2, const float* __restrict__ b2,
    const float* __restrict__ m2, const float* __restrict__ v2,
    const float* __restrict__ c3w, const float* __restrict__ c3b,
    const float* __restrict__ g3, const float* __restrict__ b3,
    const float* __restrict__ m3, const float* __restrict__ v3,
    __bf16* __restrict__ wb1, __bf16* __restrict__ wb2, __bf16* __restrict__ wb3,
    float* __restrict__ sc1, float* __restrict__ sh1,
    float* __restrict__ sc2, float* __restrict__ sh2,
    float* __restrict__ sc3, float* __restrict__ sh3)
{
    int gid = blockIdx.x * 256 + threadIdx.x;
    int gs = gridDim.x * 256;
    for (int e = gid; e < 32 * 192; e += gs) {
        int oc = e / 192, k = e % 192, rr = k >> 3, kw = k & 7;
        wb1[e] = (rr < 21 && kw >= 1) ? (__bf16)c1w[oc * 147 + rr * 7 + kw - 1]
                                      : (__bf16)0.f;
    }
    for (int e = gid; e < 64 * 384; e += gs) {
        int oc = e / 384, k = e % 384, rr = k >> 2, kw = k & 3;
        wb2[e] = (kw >= 1) ? (__bf16)c2w[oc * 288 + rr * 3 + kw - 1] : (__bf16)0.f;
    }
    for (int e = gid; e < 128 * 768; e += gs) {
        int oc = e / 768, k = e % 768, rr = k >> 2, kw = k & 3;
        wb3[e] = (kw >= 1) ? (__bf16)c3w[oc * 576 + rr * 3 + kw - 1] : (__bf16)0.f;
    }
    if (gid < 32) {
        float s = g1[gid] * rsqrtf(v1[gid] + 1e-5f);
        sc1[gid] = s; sh1[gid] = (c1b[gid] - m1[gid]) * s + b1[gid];
    } else if (gid < 96) {
        int i = gid - 32;
        float s = g2[i] * rsqrtf(v2[i] + 1e-5f);
        sc2[i] = s; sh2[i] = (c2b[i] - m2[i]) * s + b2[i];
    } else if (gid < 224) {
        int i = gid - 96;
        float s = g3[i] * rsqrtf(v3[i] + 1e-5f);
        sc3[i] = s; sh3[i] = (c3b[i] - m3[i]) * s + b3[i];
    }
}

// ============ conv1: fp32 direct, BK=64, 32oc x 256sp, 8 rows/thread ============
__global__ __launch_bounds__(256, 3) void conv1_kernel(
    const float* __restrict__ x,      // (N,3,224,224) fp32
    const __bf16* __restrict__ wb,    // (32,192) slot-shifted
    const float* __restrict__ scale, const float* __restrict__ shift,
    __bf16* __restrict__ out)         // (N,32,56,56)
{
    constexpr int IHW = 224 * 224, OHW = 56 * 56, LDR = 72;
    __shared__ __attribute__((aligned(16))) __bf16 Is[256 * LDR]; // 36.9 KB
    __shared__ __attribute__((aligned(16))) __bf16 Ws[32 * LDR];  //  4.6 KB

    const int tid = threadIdx.x;
    const int sb0 = blockIdx.x * 256;
    const int sm = tid;

    int a_n, a_ih0, a_iw0;
    {
        int m = sb0 + sm;
        a_n = m / OHW;
        int rem = m % OHW;
        a_ih0 = (rem / 56) * 4 - 3;
        a_iw0 = (rem % 56) * 4 - 3;
    }
    unsigned ihok = 0;
    #pragma unroll
    for (int t = 0; t < 7; ++t)
        ihok |= (unsigned)(((a_ih0 + t) >= 0) && ((a_ih0 + t) < 224)) << t;
    const bool left = (a_iw0 < 0);
    const int boff = a_n * 3 * IHW + a_ih0 * 224 + (a_iw0 - 1);  // 16B-aligned

    const int w_oc = tid >> 3, w_j = tid & 7;
    const int wave = tid >> 6, lane = tid & 63;
    const int quad = lane >> 4, l16 = lane & 15;

    f32x4 acc[2][4] = {};

    #pragma unroll
    for (int ci = 0; ci < 3; ++ci) {
        const int k0 = ci * 64;
        bf16x8 hv[8];
        #pragma unroll
        for (int r = 0; r < 8; ++r) {
            const int rr = ci * 8 + r;                    // compile-time
            if (rr >= 21) {
                hv[r] = (bf16x8){};
            } else {
                const int ic = rr / 7, kh = rr % 7;
                int off = boff + (ic * IHW + kh * 224);
                int o0 = off < 0 ? 0 : off;
                int o1 = (off + 4) < 0 ? 0 : (off + 4);
                float4 A = *(const float4*)(x + o0);
                float4 B = *(const float4*)(x + o1);
                float va[8] = {A.x, A.y, A.z, A.w, B.x, B.y, B.z, B.w};
                bool rok = (ihok >> kh) & 1u;
                #pragma unroll
                for (int j = 0; j < 8; ++j) va[j] = rok ? va[j] : 0.f;
                #pragma unroll
                for (int j = 1; j <= 3; ++j) va[j] = left ? 0.f : va[j];
                bf16x8 h;
                #pragma unroll
                for (int j = 0; j < 8; ++j) h[j] = (__bf16)va[j];
                hv[r] = h;
            }
        }
        bf16x8 wv = *(const bf16x8*)&wb[(size_t)w_oc * 192 + k0 + w_j * 8];

        __syncthreads();
        #pragma unroll
        for (int r = 0; r < 8; ++r)
            *(bf16x8*)&Is[sm * LDR + r * 8] = hv[r];
        *(bf16x8*)&Ws[w_oc * LDR + w_j * 8] = wv;
        __syncthreads();

        #pragma unroll
        for (int kk = 0; kk < 2; ++kk) {
            bf16x8 afr[2], bfr[4];
            #pragma unroll
            for (int mt = 0; mt < 2; ++mt)
                afr[mt] = *(const bf16x8*)&Ws[(mt * 16 + l16) * LDR + kk * 32 + quad * 8];
            #pragma unroll
            for (int nt = 0; nt < 4; ++nt)
                bfr[nt] = *(const bf16x8*)&Is[(wave * 64 + nt * 16 + l16) * LDR + kk * 32 + quad * 8];
            #pragma unroll
            for (int mt = 0; mt < 2; ++mt)
                #pragma unroll
                for (int nt = 0; nt < 4; ++nt)
                    acc[mt][nt] = __builtin_amdgcn_mfma_f32_16x16x32_bf16(
                        afr[mt], bfr[nt], acc[mt][nt], 0, 0, 0);
        }
    }

    #pragma unroll
    for (int mt = 0; mt < 2; ++mt) {
        #pragma unroll
        for (int r = 0; r < 4; ++r) {
            int oc = mt * 16 + quad * 4 + r;
            float scl = scale[oc], shf = shift[oc];
            #pragma unroll
            for (int nt = 0; nt < 4; ++nt) {
                int sg = sb0 + wave * 64 + nt * 16 + l16;
                int n = sg / OHW, s = sg % OHW;
                float v = fmaf(acc[mt][nt][r], scl, shf);
                v = v > 0.f ? v : 0.f;
                out[((size_t)n * 32 + oc) * OHW + s] = (__bf16)v;
            }
        }
    }
}

// ============ generic bf16 conv body, BK=64, 256sp, 16 rows/thread ============
template<int NOCT, int IC, int IH, int IW, int OH, int OW, int OC,
         int KTP, int KCH, int GXS>
DEV void conv_body64(
    const __bf16* __restrict__ xo,
    const __bf16* __restrict__ wb,
    const float* __restrict__ scale, const float* __restrict__ shift,
    __bf16* __restrict__ out, __bf16* Is, __bf16* Ws)
{
    constexpr int KS = 3, S = 2, P = 1;
    constexpr int KITER = KCH / 64;
    constexpr int OHW = OH * OW;
    constexpr int IHW = IH * IW;
    constexpr int LDR = 72;
    constexpr int WLD = NOCT / 2;     // weight bf16x8 per thread (2 or 1)

    const int tid = threadIdx.x;
    int bx = blockIdx.x;
    if (GXS > 0) bx = (bx & 7) * GXS + (bx >> 3);
    const int sb0 = bx * 256;
    const int oc0 = blockIdx.y * (NOCT * 16);

    const int sm = tid;
    int a_n, a_ih0, a_iw0;
    {
        int m = sb0 + sm;
        a_n = m / OHW;
        int rem = m % OHW;
        a_ih0 = (rem / OW) * S - P;
        a_iw0 = (rem % OW) * S - P;
    }
    unsigned ihok = 0;
    #pragma unroll
    for (int t = 0; t < KS; ++t)
        ihok |= (unsigned)(((a_ih0 + t) >= 0) && ((a_ih0 + t) < IH)) << t;
    const bool left = (a_iw0 < 0);
    const __bf16* xp = xo + ((size_t)a_n * IC * IHW + (ptrdiff_t)a_ih0 * IW
                             + (a_iw0 - 1));

    const int wave = tid >> 6, lane = tid & 63;
    const int quad = lane >> 4, l16 = lane & 15;

    f32x4 acc[NOCT][4] = {};

    #pragma unroll
    for (int ci = 0; ci < KITER; ++ci) {
        const int k0 = ci * 64;

        // ---- 16 whole rows of 4 halfs: unpredicated dwordx2 loads (128 B in flight) ----
        union { unsigned u[32]; bf16x8 v[8]; } Pk;
        #pragma unroll
        for (int r = 0; r < 16; ++r) {
            const int rr = (k0 / 4) + r;                  // compile-time
            const int ic = rr / KS, kh = rr % KS;
            const unsigned* rp = (const unsigned*)(xp + (ic * IHW + kh * IW));
            unsigned t0 = rp[0], t1 = rp[1];
            bool rok = (ihok >> kh) & 1u;
            t0 = rok ? t0 : 0u;
            t1 = rok ? t1 : 0u;
            t0 = left ? (t0 & 0x0000FFFFu) : t0;          // clear slot 1 (P=1)
            Pk.u[r * 2]     = t0;
            Pk.u[r * 2 + 1] = t1;
        }
        bf16x8 wv[WLD];
        #pragma unroll
        for (int i = 0; i < WLD; ++i) {
            int e = i * 256 + tid;
            wv[i] = *(const bf16x8*)&wb[(size_t)(oc0 + (e >> 3)) * KTP + k0 + (e & 7) * 8];
        }

        __syncthreads();
        #pragma unroll
        for (int q = 0; q < 8; ++q)
            *(bf16x8*)&Is[sm * LDR + q * 8] = Pk.v[q];
        #pragma unroll
        for (int i = 0; i < WLD; ++i) {
            int e = i * 256 + tid;
            *(bf16x8*)&Ws[(e >> 3) * LDR + (e & 7) * 8] = wv[i];
        }
        __syncthreads();

        #pragma unroll
        for (int kk = 0; kk < 2; ++kk) {
            bf16x8 afr[NOCT], bfr[4];
            #pragma unroll
            for (int mt = 0; mt < NOCT; ++mt)
                afr[mt] = *(const bf16x8*)&Ws[(mt * 16 + l16) * LDR + kk * 32 + quad * 8];
            #pragma unroll
            for (int nt = 0; nt < 4; ++nt)
                bfr[nt] = *(const bf16x8*)&Is[(wave * 64 + nt * 16 + l16) * LDR + kk * 32 + quad * 8];
            #pragma unroll
            for (int mt = 0; mt < NOCT; ++mt)
                #pragma unroll
                for (int nt = 0; nt < 4; ++nt)
                    acc[mt][nt] = __builtin_amdgcn_mfma_f32_16x16x32_bf16(
                        afr[mt], bfr[nt], acc[mt][nt], 0, 0, 0);
        }
    }

    #pragma unroll
    for (int mt = 0; mt < NOCT; ++mt) {
        #pragma unroll
        for (int r = 0; r < 4; ++r) {
            int oc = oc0 + mt * 16 + quad * 4 + r;
            float scl = scale[oc], shf = shift[oc];
            #pragma unroll
            for (int nt = 0; nt < 4; ++nt) {
                int sg = sb0 + wave * 64 + nt * 16 + l16;
                int n = sg / OHW, s = sg % OHW;
                float v = fmaf(acc[mt][nt][r], scl, shf);
                v = v > 0.f ? v : 0.f;
                out[((size_t)n * OC + oc) * OHW + s] = (__bf16)v;
            }
        }
    }
}

__global__ __launch_bounds__(256, 3) void conv2_kernel(
    const __bf16* __restrict__ xo, const __bf16* __restrict__ wb,
    const float* __restrict__ scale, const float* __restrict__ shift,
    __bf16* __restrict__ out)
{
    __shared__ __attribute__((aligned(16))) __bf16 Is[256 * 72]; // 36.9 KB
    __shared__ __attribute__((aligned(16))) __bf16 Ws[64 * 72];  //  9.2 KB
    conv_body64<4, 32, 56, 56, 28, 28, 64, 384, 384, 49>(        // 392 = 8*49
        xo, wb, scale, shift, out, Is, Ws);
}

__global__ __launch_bounds__(256, 3) void conv3_kernel(
    const __bf16* __restrict__ xo, const __bf16* __restrict__ wb,
    const float* __restrict__ scale, const float* __restrict__ shift,
    __bf16* __restrict__ out)
{
    __shared__ __attribute__((aligned(16))) __bf16 Is[256 * 72];
    __shared__ __attribute__((aligned(16))) __bf16 Ws[32 * 72];
    conv_body64<2, 64, 28, 28, 14, 14, 128, 768, 768, 0>(        // (98,4) grid
        xo, wb, scale, shift, out, Is, Ws);
}

// ============ head: slab -> pool -> linear/tanh -> shuffle circuit -> MLP ============
__global__ __launch_bounds__(256) void head_kernel(
    const __bf16* __restrict__ c3o,      // (N,128,14,14)
    const float* __restrict__ pre_w, const float* __restrict__ pre_b,
    const float* __restrict__ qw,
    const float* __restrict__ pw1, const float* __restrict__ pb1,
    const float* __restrict__ pw2, const float* __restrict__ pb2,
    float* __restrict__ out)             // (N,5)
{
    __shared__ __attribute__((aligned(16))) __bf16 slab[128 * 196]; // 49 KB
    __shared__ float f[512];
    __shared__ float ang[4];
    __shared__ float zexp[4];
    __shared__ float h1[64];

    int b = blockIdx.x;
    int t = threadIdx.x;

    {
        const bf16x8* src = (const bf16x8*)(c3o + (size_t)b * 128 * 196);
        bf16x8* dst = (bf16x8*)slab;
        #pragma unroll
        for (int i = 0; i < 13; ++i) {
            int e = t + i * 256;
            if (e < 3136) dst[e] = src[e];
        }
    }
    __syncthreads();

    for (int p = t; p < 512; p += 256) {
        int c = p >> 2, i = (p >> 1) & 1, j = p & 1;
        int base = c * 196 + (i * 7) * 14 + j * 7;
        float s = 0.f;
        #pragma unroll
        for (int u = 0; u < 7; ++u)
            #pragma unroll
            for (int v = 0; v < 7; ++v)
                s += (float)slab[base + u * 14 + v];
        f[p] = s * (1.f / 49.f);
    }
    __syncthreads();

    int wv = t >> 6, lane = t & 63;
    float partial = 0.f;
    for (int d = lane; d < 512; d += 64)
        partial += f[d] * pre_w[wv * 512 + d];
    #pragma unroll
    for (int off = 32; off > 0; off >>= 1)
        partial += __shfl_down(partial, off, 64);
    if (lane == 0)
        ang[wv] = tanhf(partial + pre_b[wv]) * 3.14159265358979323846f;
    __syncthreads();

    if (t < 16) {
        const int i = t;
        float re = (i == 0) ? 1.f : 0.f;
        float im = 0.f;

        #pragma unroll
        for (int q = 0; q < 4; ++q) {
            const int m = 8 >> q;
            float th = ang[q] * 0.5f;
            float c = cosf(th), s = sinf(th);
            float pr = __shfl_xor(re, m, 64);
            float pi = __shfl_xor(im, m, 64);
            float ts = (i & m) ? s : -s;
            re = c * re + ts * pr;
            im = c * im + ts * pi;
        }
        #pragma unroll
        for (int l = 0; l < 2; ++l) {
            #pragma unroll
            for (int q = 0; q < 4; ++q) {
                const int m = 8 >> q;
                const float* qq = qw + (l * 4 + q) * 3;
                {   // RX
                    float th = qq[0] * 0.5f;
                    float c = cosf(th), s = sinf(th);
                    float pr = __shfl_xor(re, m, 64);
                    float pi = __shfl_xor(im, m, 64);
                    float rn = c * re + s * pi;
                    im = c * im - s * pr;
                    re = rn;
                }
                {   // RY
                    float th = qq[1] * 0.5f;
                    float c = cosf(th), s = sinf(th);
                    float pr = __shfl_xor(re, m, 64);
                    float pi = __shfl_xor(im, m, 64);
                    float ts = (i & m) ? s : -s;
                    re = c * re + ts * pr;
                    im = c * im + ts * pi;
                }
                {   // RZ
                    float th = qq[2] * 0.5f;
                    float c = cosf(th), s = sinf(th);
                    float ts = (i & m) ? s : -s;
                    float rn = c * re - ts * im;
                    im = c * im + ts * re;
                    re = rn;
                }
            }
            #pragma unroll
            for (int e = 0; e < 4; ++e) {
                const int cm = 8 >> e, tm = 8 >> ((e + 1) & 3);
                float pr = __shfl_xor(re, tm, 64);
                float pi = __shfl_xor(im, tm, 64);
                bool sw = (i & cm) != 0;
                re = sw ? pr : re;
                im = sw ? pi : im;
            }
        }
        float p2 = re * re + im * im;
        #pragma unroll
        for (int q = 0; q < 4; ++q) {
            const int m = 8 >> q;
            float v = (i & m) ? -p2 : p2;
            v += __shfl_xor(v, 1, 64);
            v += __shfl_xor(v, 2, 64);
            v += __shfl_xor(v, 4, 64);
            v += __shfl_xor(v, 8, 64);
            if (i == 0) zexp[q] = v;
        }
    }
    __syncthreads();

    if (t < 64) {
        float s = pb1[t];
        #pragma unroll
        for (int k = 0; k < 4; ++k) s += zexp[k] * pw1[t * 4 + k];
        h1[t] = s > 0.f ? s : 0.f;
    }
    __syncthreads();

    if (t < 5) {
        float s = pb2[t];
        for (int k = 0; k < 64; ++k) s += h1[k] * pw2[t * 64 + k];
        out[b * 5 + t] = s;
    }
}

extern "C" void kernel_launch(void* const* d_in, const int* in_sizes, int n_in,
                              void* d_out, int out_size, void* d_ws, size_t ws_size,
                              hipStream_t stream) {
    const float* x    = (const float*)d_in[0];
    const float* c1w  = (const float*)d_in[1];
    const float* c1b  = (const float*)d_in[2];
    const float* bn1g = (const float*)d_in[3];
    const float* bn1b = (const float*)d_in[4];
    const float* bn1m = (const float*)d_in[5];
    const float* bn1v = (const float*)d_in[6];
    const float* c2w  = (const float*)d_in[7];
    const float* c2b  = (const float*)d_in[8];
    const float* bn2g = (const float*)d_in[9];
    const float* bn2b = (const float*)d_in[10];
    const float* bn2m = (const float*)d_in[11];
    const float* bn2v = (const float*)d_in[12];
    const float* c3w  = (const float*)d_in[13];
    const float* c3bi = (const float*)d_in[14];
    const float* bn3g = (const float*)d_in[15];
    const float* bn3b = (const float*)d_in[16];
    const float* bn3m = (const float*)d_in[17];
    const float* bn3v = (const float*)d_in[18];
    const float* prw  = (const float*)d_in[19];
    const float* prb  = (const float*)d_in[20];
    const float* qw   = (const float*)d_in[21];
    const float* pw1  = (const float*)d_in[22];
    const float* pb1  = (const float*)d_in[23];
    const float* pw2  = (const float*)d_in[24];
    const float* pb2  = (const float*)d_in[25];

    const int N = in_sizes[0] / (3 * 224 * 224);   // 128
    const size_t NC1 = (size_t)N * 32 * 56 * 56;
    const size_t NC2 = (size_t)N * 64 * 28 * 28;
    const size_t NC3 = (size_t)N * 128 * 14 * 14;

    __bf16* ws_h = (__bf16*)d_ws;
    __bf16* c1o = ws_h + 64;
    __bf16* c2o = ws_h + 64 + NC1 + 64 + 64;
    __bf16* c3o = ws_h + 64 + NC1 + 64 + 64 + NC2 + 64;
    __bf16* wb1 = c3o + NC3;
    __bf16* wb2 = wb1 + 32 * 192;
    __bf16* wb3 = wb2 + 64 * 384;
    float* sc1 = (float*)(wb3 + 128 * 768);
    float* sh1 = sc1 + 32;
    float* sc2 = sh1 + 32;  float* sh2 = sc2 + 64;
    float* sc3 = sh2 + 64;  float* sh3 = sc3 + 128;

    prep_weights<<<192, 256, 0, stream>>>(
        c1w, c1b, bn1g, bn1b, bn1m, bn1v,
        c2w, c2b, bn2g, bn2b, bn2m, bn2v,
        c3w, c3bi, bn3g, bn3b, bn3m, bn3v,
        wb1, wb2, wb3, sc1, sh1, sc2, sh2, sc3, sh3);

    conv1_kernel<<<dim3(401408 / 256, 1), 256, 0, stream>>>(x, wb1, sc1, sh1, c1o);
    conv2_kernel<<<dim3(100352 / 256, 1), 256, 0, stream>>>(c1o, wb2, sc2, sh2, c2o);
    conv3_kernel<<<dim3(25088 / 256, 4), 256, 0, stream>>>(c2o, wb3, sc3, sh3, c3o);
    head_kernel<<<N, 256, 0, stream>>>(c3o, prw, prb, qw,
                                       pw1, pb1, pw2, pb2, (float*)d_out);
}